// Round 9
// baseline (8077.787 us; speedup 1.0000x reference)
//
#include <hip/hip_runtime.h>

typedef __attribute__((ext_vector_type(8))) short short8;
typedef __attribute__((ext_vector_type(4))) float f32x4;
typedef __attribute__((ext_vector_type(4))) unsigned int u32x4;

#define MFMA(a,b,c) __builtin_amdgcn_mfma_f32_16x16x32_bf16((a),(b),(c),0,0,0)

#define B_  16
#define S_  512
#define DM_ 768
#define H_  640
#define G4_ 2560
#define DA_ 1280
#define NH_ 10
#define HD_ 128
#define U_   20      // hidden units per WG
#define NQ_  110     // 8B chunks per producer (107 data + 3 tag-only pads)
#define SLAB8_ 896   // bytes per producer slab (110*8 -> pad to 896)

static __device__ __forceinline__ unsigned short f2bf(float v) {
  unsigned u = __builtin_bit_cast(unsigned, v);
  u = (u + 0x7fffu + ((u >> 16) & 1u)) >> 16;
  return (unsigned short)u;
}
static __device__ __forceinline__ float bf2f(unsigned short u) {
  return __builtin_bit_cast(float, (unsigned)u << 16);
}
static __device__ __forceinline__ float sigm(float x) { return 1.0f / (1.0f + __expf(-x)); }
static __device__ __forceinline__ float tanh_c(float x) {
  x = fminf(fmaxf(x, -15.0f), 15.0f);
  float e = __expf(2.0f * x);
  return (e - 1.0f) / (e + 1.0f);
}

// ---- LLC-coherent access. 8B qword = single transaction (R4 HW-validated);
// tag and payload share the qword => tag-valid implies payload-valid.
static __device__ __forceinline__ unsigned long long load_coh64(const void* p) {
  unsigned long long r;
  asm volatile("global_load_dwordx2 %0, %1, off sc0 sc1"
               : "=v"(r) : "v"(p) : "memory");
  return r;
}
static __device__ __forceinline__ void store_coh64(void* p, unsigned long long v) {
  asm volatile("global_store_dwordx2 %0, %1, off sc0 sc1"
               :: "v"(p), "v"(v) : "memory");
}
#define WAIT_VM0() asm volatile("s_waitcnt vmcnt(0)" ::: "memory")

// barrier that does NOT drain vmcnt (keeps prefetches/stores in flight)
static __device__ __forceinline__ void bar_lgkm() {
  __builtin_amdgcn_sched_barrier(0);
  asm volatile("s_waitcnt lgkmcnt(0)\n\ts_barrier" ::: "memory");
  __builtin_amdgcn_sched_barrier(0);
}

// ---------------------------------------------------------------- cast f32->bf16
__global__ __launch_bounds__(256)
void cast_f32_bf16(const float* __restrict__ src, unsigned short* __restrict__ dst, int n4) {
  int i = blockIdx.x * 256 + threadIdx.x;
  if (i >= n4) return;
  float4 v = reinterpret_cast<const float4*>(src)[i];
  ushort4 o;
  o.x = f2bf(v.x); o.y = f2bf(v.y); o.z = f2bf(v.z); o.w = f2bf(v.w);
  reinterpret_cast<ushort4*>(dst)[i] = o;
}

// ---------------------------------------------------------------- GEMM  C = A @ W^T + bias
// OUT_MODE 1: bf16 C[M][N]; 2: bf16 per-head-transposed V;
// 3: f32 xp-scatter [slice(32)][t][u(20)][gate(4)][b(16)]; 4: bf16 same layout.
__device__ __forceinline__ void gload_lds16(void* lds, const void* g) {
  __builtin_amdgcn_global_load_lds(
      (const __attribute__((address_space(1))) unsigned int*)g,
      (__attribute__((address_space(3))) unsigned int*)lds, 16, 0, 0);
}

template<int OUT_MODE>
__global__ __launch_bounds__(256)
void gemm_abt(const unsigned short* __restrict__ A, const unsigned short* __restrict__ W,
              const float* __restrict__ bias, void* __restrict__ Cout,
              int M, int N, int K) {
  __shared__ unsigned short lA[128 * 32];
  __shared__ unsigned short lB[128 * 32];
  const int tid = threadIdx.x;
  const int lane = tid & 63, wid = tid >> 6;
  const int nbn = N >> 7;
  const int mi = blockIdx.x / nbn, ni = blockIdx.x % nbn;
  const int l15 = lane & 15, lq = lane >> 4;

  f32x4 acc[4][4] = {};

  for (int k0 = 0; k0 < K; k0 += 32) {
#pragma unroll
    for (int part = 0; part < 2; ++part) {
      int linear = part * 256 + tid;
      int r = linear >> 2, cc = linear & 3;
      const unsigned short* ga = A + (size_t)(mi * 128 + r) * K + k0 + cc * 8;
      const unsigned short* gb = W + (size_t)(ni * 128 + r) * K + k0 + cc * 8;
      gload_lds16(&lA[(part * 256 + wid * 64) * 8], ga);
      gload_lds16(&lB[(part * 256 + wid * 64) * 8], gb);
    }
    __syncthreads();
    const int wm = (wid >> 1) * 64, wn = (wid & 1) * 64;
    short8 af[4], bfr[4];
#pragma unroll
    for (int m = 0; m < 4; ++m)
      af[m] = *(const short8*)&lA[(wm + m * 16 + l15) * 32 + lq * 8];
#pragma unroll
    for (int n = 0; n < 4; ++n)
      bfr[n] = *(const short8*)&lB[(wn + n * 16 + l15) * 32 + lq * 8];
#pragma unroll
    for (int m = 0; m < 4; ++m)
#pragma unroll
      for (int n = 0; n < 4; ++n)
        acc[m][n] = MFMA(af[m], bfr[n], acc[m][n]);
    __syncthreads();
  }

  const int wm = (wid >> 1) * 64, wn = (wid & 1) * 64;
#pragma unroll
  for (int n = 0; n < 4; ++n) {
    int col = ni * 128 + wn + n * 16 + l15;
    float bv = bias[col];
#pragma unroll
    for (int m = 0; m < 4; ++m) {
#pragma unroll
      for (int r = 0; r < 4; ++r) {
        int row = mi * 128 + wm + m * 16 + lq * 4 + r;
        float v = acc[m][n][r] + bv;
        if (OUT_MODE == 1) {
          ((unsigned short*)Cout)[(size_t)row * N + col] = f2bf(v);
        } else if (OUT_MODE == 2) {
          int bb = row >> 9, s = row & 511, hh = col >> 7, d = col & 127;
          ((unsigned short*)Cout)[(((size_t)(bb * NH_ + hh) * HD_ + d) << 9) + s] = f2bf(v);
        } else {
          int gate = col / 640, un = col % 640;
          int sl = un / U_, uu = un % U_;
          int bb = row >> 9, tt = row & 511;
          size_t idx = ((((size_t)sl * S_ + tt) * U_ + uu) * 4 + gate) * 16 + bb;
          if (OUT_MODE == 3) ((float*)Cout)[idx] = v;
          else               ((unsigned short*)Cout)[idx] = f2bf(v);
        }
      }
    }
  }
}

// ---------------------------------------------------------------- persistent BiLSTM layer
// 64 WGs (32/dir) x 320 thr. Exchange = R4-validated 8B seqlock chunks
// {3 bf16, tag16}: single-transaction coherent qword => tag-valid implies
// payload-valid. Publish = 110 fire-and-forget qwords (no drain, no flag).
// Consume = 11 pre-issued qword loads/thread (issued the step BEFORE, so the
// LLC round trip hides under MFMA+gates), retry until tags >= s.
// Anti-overwrite (2 parity slabs): P writes s+2 only after P consumed s+1,
// which required every WG's publish of s+1, each after that WG consumed s.
// Tags per-layer (memset between layers); zero tag == valid h_0 = 0.
template<bool XPF32>
__global__ __launch_bounds__(320)
void bilstm_layer(const void* __restrict__ xp_,            // [2][32][S][20][4][16]
                  const unsigned short* __restrict__ whh_g,// [2][2560][640] bf16
                  const int* __restrict__ lengths,
                  char* __restrict__ h_ex,                 // [2 dir][2 par][32 p][SLAB8_]
                  unsigned short* __restrict__ out_bf)     // [B*S][1280] bf16
{
  __shared__ unsigned short whh[80 * 648];     // row = uloc*4+gate
  __shared__ unsigned short hbuf[16 * 648];    // [b][640 units]
  __shared__ unsigned short staged[336];       // [b][20 units] + zero pad

  const int tid = threadIdx.x, lane = tid & 63, w = tid >> 6;
  const int wg = blockIdx.x, dir = wg >> 5, slice = wg & 31;
  const int J0 = slice * U_;
  const int l15 = lane & 15, lq = lane >> 4;
  const int u4 = l15 >> 2, gate = l15 & 3;
  const int uloc = w * 4 + u4;

  // stage Whh slab, gate-interleaved rows (row r: gate=r&3, unit=r>>2)
  for (int c = tid; c < 6400; c += 320) {
    int r = c / 80, col = c % 80;
    int grow = (r & 3) * H_ + J0 + (r >> 2);
    *(u32x4*)&whh[r * 648 + col * 8] =
        *(const u32x4*)&whh_g[((size_t)dir * G4_ + grow) * H_ + col * 8];
  }
  int lenv[4];
#pragma unroll
  for (int r = 0; r < 4; ++r) lenv[r] = lengths[lq * 4 + r];
  if (tid < 16) staged[320 + tid] = 0;   // finite pad for chunks 107..109

  __syncthreads();

  float cst[4] = {0,0,0,0}, hst[4] = {0,0,0,0};

  const char* xps = (const char*)xp_ +
      ((size_t)dir * 32 + slice) * S_ * 1280 * (XPF32 ? 4 : 2);
  const int xoff = (uloc * 4 + gate) * 16 + lq * 4;

  float4 xvf, xnf; ushort4 xvh, xnh;
  {
    int t0 = dir ? (S_ - 1) : 0;
    if (XPF32) xvf = *(const float4*)(xps + ((size_t)t0 * 1280 + xoff) * 4);
    else       xvh = *(const ushort4*)(xps + ((size_t)t0 * 1280 + xoff) * 2);
  }

  // exchange addressing (R4-proven consumer map: 10 threads/producer, 11 chunks)
  const char* par_img0 = h_ex + (size_t)dir * (2 * 32 * SLAB8_);
  const char* par_img1 = par_img0 + 32 * SLAB8_;
  char* own0 = (char*)par_img0 + (size_t)slice * SLAB8_;
  char* own1 = (char*)par_img1 + (size_t)slice * SLAB8_;
  const int cp  = tid / 10;          // producer 0..31
  const int qi0 = (tid % 10) * 11;   // first chunk 0..99
  const char* src0 = par_img0 + (size_t)cp * SLAB8_ + (size_t)qi0 * 8;
  const char* src1 = par_img1 + (size_t)cp * SLAB8_ + (size_t)qi0 * 8;

  unsigned long long qv[11];
  // pre-issue loads for step 0 (parity 0; zero-init == tag 0, payload h_0 = 0)
#pragma unroll
  for (int j = 0; j < 11; ++j) qv[j] = load_coh64(src0 + j * 8);

  for (int s = 0; s < S_; ++s) {
    const int t = dir ? (S_ - 1 - s) : s;
    const char* sb = (s & 1) ? src1 : src0;

    // ---- poll: 16-bit tag in each qword validates its own payload
    for (;;) {
      WAIT_VM0();
      __builtin_amdgcn_sched_barrier(0);
      bool ok = true;
#pragma unroll
      for (int j = 0; j < 11; ++j) ok &= ((int)(qv[j] >> 48) >= s);
      if (__all(ok)) break;
      __builtin_amdgcn_s_sleep(1);
#pragma unroll
      for (int j = 0; j < 11; ++j) qv[j] = load_coh64(sb + j * 8);
    }
    // scatter payloads to hbuf (R4-proven mapping; pads skipped by guards)
#pragma unroll
    for (int j = 0; j < 11; ++j) {
      int off0 = (qi0 + j) * 3;
      unsigned short v0 = (unsigned short)(qv[j]);
      unsigned short v1 = (unsigned short)(qv[j] >> 16);
      unsigned short v2 = (unsigned short)(qv[j] >> 32);
      if (off0 < 320)     hbuf[(off0 / 20) * 648 + cp * U_ + (off0 % 20)] = v0;
      if (off0 + 1 < 320) hbuf[((off0 + 1) / 20) * 648 + cp * U_ + ((off0 + 1) % 20)] = v1;
      if (off0 + 2 < 320) hbuf[((off0 + 2) / 20) * 648 + cp * U_ + ((off0 + 2) % 20)] = v2;
    }
    bar_lgkm();   // hbuf = h_s ready

    // ---- MFMA: pre[b=lq*4+r][gaterow=l15] for this wave's 16 gate-rows
    f32x4 a0 = {0,0,0,0}, a1 = {0,0,0,0};
#pragma unroll
    for (int kk = 0; kk < 20; kk += 2) {
      short8 av0 = *(const short8*)&hbuf[l15 * 648 + kk * 32 + lq * 8];
      short8 bv0 = *(const short8*)&whh[(w * 16 + l15) * 648 + kk * 32 + lq * 8];
      a0 = MFMA(av0, bv0, a0);
      short8 av1 = *(const short8*)&hbuf[l15 * 648 + (kk + 1) * 32 + lq * 8];
      short8 bv1 = *(const short8*)&whh[(w * 16 + l15) * 648 + (kk + 1) * 32 + lq * 8];
      a1 = MFMA(av1, bv1, a1);
    }

    // ---- gates via quad shfl (lane = (u4,gate), b = lq*4+r)
    bool vld[4];
#pragma unroll
    for (int r = 0; r < 4; ++r) {
      float xq = XPF32 ? ((const float*)&xvf)[r] : bf2f(((const unsigned short*)&xvh)[r]);
      float pre = a0[r] + a1[r] + xq;
      float x1 = __shfl_xor(pre, 1);
      float x2 = __shfl_xor(pre, 2);
      float x3 = __shfl_xor(pre, 3);
      float ip = gate == 0 ? pre : gate == 1 ? x1 : gate == 2 ? x2 : x3;
      float fp = gate == 0 ? x1 : gate == 1 ? pre : gate == 2 ? x3 : x2;
      float gp = gate == 0 ? x2 : gate == 1 ? x3 : gate == 2 ? pre : x1;
      float op = gate == 0 ? x3 : gate == 1 ? x2 : gate == 2 ? x1 : pre;
      float i_ = sigm(ip), f_ = sigm(fp);
      float g_ = tanh_c(gp), o_ = sigm(op);
      float c2 = f_ * cst[r] + i_ * g_;
      float h2 = o_ * tanh_c(c2);
      vld[r] = t < lenv[r];
      cst[r] = vld[r] ? c2 : cst[r];
      hst[r] = vld[r] ? h2 : hst[r];
      if (gate == 0) staged[(lq * 4 + r) * U_ + uloc] = f2bf(hst[r]);
    }
    bar_lgkm();   // staged complete; hbuf fully consumed

    if (s + 1 < S_) {
      // ---- publish: 110 fire-and-forget tagged qwords (no drain, no flag)
      if (tid < NQ_) {
        unsigned long long q =
              (unsigned long long)staged[tid * 3]
            | ((unsigned long long)staged[tid * 3 + 1] << 16)
            | ((unsigned long long)staged[tid * 3 + 2] << 32)
            | ((unsigned long long)(unsigned)(s + 1) << 48);
        store_coh64(((s + 1) & 1 ? own1 : own0) + (size_t)tid * 8, q);
      }
      // ---- pre-issue consumer loads for step s+1 (RT hides under next compute)
      const char* nb = ((s + 1) & 1) ? src1 : src0;
#pragma unroll
      for (int j = 0; j < 11; ++j) qv[j] = load_coh64(nb + j * 8);
    }

    // ---- off-critical-path: output stores + next xp prefetch
    if (gate == 0) {
#pragma unroll
      for (int r = 0; r < 4; ++r) {
        int b = lq * 4 + r;
        out_bf[((size_t)(b * S_ + t)) * DA_ + dir * H_ + J0 + uloc] =
            f2bf(vld[r] ? hst[r] : 0.f);
      }
    }
    {
      int tn = dir ? (S_ - 2 - s) : (s + 1);
      tn = tn < 0 ? 0 : (tn > S_ - 1 ? S_ - 1 : tn);
      if (XPF32) xnf = *(const float4*)(xps + ((size_t)tn * 1280 + xoff) * 4);
      else       xnh = *(const ushort4*)(xps + ((size_t)tn * 1280 + xoff) * 2);
    }
    xvf = xnf; xvh = xnh;
  }
}

// ---------------------------------------------------------------- fused attention + residual
__global__ __launch_bounds__(256)
void attn_fused(const unsigned short* __restrict__ q, const unsigned short* __restrict__ k,
                const unsigned short* __restrict__ vT, const float* __restrict__ mask,
                const unsigned short* __restrict__ h1, float* __restrict__ out)
{
  __shared__ unsigned short p_lds[64 * 512];
  const int tid = threadIdx.x, lane = tid & 63, wid = tid >> 6;
  const int bx = blockIdx.x;
  const int b = bx / 80, rem = bx % 80, h = rem / 8, qt = rem % 8;
  const int l15 = lane & 15, lq = lane >> 4;
  const int qrow0 = qt * 64 + wid * 16;

  short8 qf[4];
  {
    const unsigned short* qb = q + ((size_t)(b * S_ + qrow0 + l15)) * DA_ + h * HD_ + lq * 8;
#pragma unroll
    for (int ks = 0; ks < 4; ++ks) qf[ks] = *(const short8*)(qb + ks * 32);
  }
  f32x4 sc[32];
#pragma unroll
  for (int nt = 0; nt < 32; ++nt) {
    f32x4 a = {0.f, 0.f, 0.f, 0.f};
    const unsigned short* kb = k + ((size_t)(b * S_ + nt * 16 + l15)) * DA_ + h * HD_ + lq * 8;
#pragma unroll
    for (int ks = 0; ks < 4; ++ks) {
      short8 bf = *(const short8*)(kb + ks * 32);
      a = MFMA(qf[ks], bf, a);
    }
    sc[nt] = a;
  }
  const float scl = 0.08838834764831845f;  // 1/sqrt(128)
  float mx[4] = {-1e30f, -1e30f, -1e30f, -1e30f};
#pragma unroll
  for (int nt = 0; nt < 32; ++nt) {
    float mv = mask[b * S_ + nt * 16 + l15];
#pragma unroll
    for (int r = 0; r < 4; ++r) {
      float v = sc[nt][r] * scl + mv;
      sc[nt][r] = v;
      mx[r] = fmaxf(mx[r], v);
    }
  }
#pragma unroll
  for (int r = 0; r < 4; ++r) {
    mx[r] = fmaxf(mx[r], __shfl_xor(mx[r], 1));
    mx[r] = fmaxf(mx[r], __shfl_xor(mx[r], 2));
    mx[r] = fmaxf(mx[r], __shfl_xor(mx[r], 4));
    mx[r] = fmaxf(mx[r], __shfl_xor(mx[r], 8));
  }
  float sm[4] = {0.f, 0.f, 0.f, 0.f};
#pragma unroll
  for (int nt = 0; nt < 32; ++nt)
#pragma unroll
    for (int r = 0; r < 4; ++r) {
      float p = __expf(sc[nt][r] - mx[r]);
      sc[nt][r] = p; sm[r] += p;
    }
#pragma unroll
  for (int r = 0; r < 4; ++r) {
    sm[r] += __shfl_xor(sm[r], 1);
    sm[r] += __shfl_xor(sm[r], 2);
    sm[r] += __shfl_xor(sm[r], 4);
    sm[r] += __shfl_xor(sm[r], 8);
    sm[r] = 1.0f / sm[r];
  }
#pragma unroll
  for (int nt = 0; nt < 32; ++nt)
#pragma unroll
    for (int r = 0; r < 4; ++r) {
      int row = wid * 16 + lq * 4 + r;
      int byte = row * 1024 + (nt * 16 + l15) * 2;
      byte ^= (row & 7) << 4;
      *(unsigned short*)((char*)p_lds + byte) = f2bf(sc[nt][r] * sm[r]);
    }
  __syncthreads();

  f32x4 oa[8] = {};
#pragma unroll
  for (int kk = 0; kk < 16; ++kk) {
    int row = wid * 16 + l15;
    int byte = row * 1024 + (kk * 32 + lq * 8) * 2;
    byte ^= (row & 7) << 4;
    short8 pa = *(const short8*)((char*)p_lds + byte);
    const unsigned short* vb = vT + ((size_t)(b * NH_ + h) * HD_ + l15) * S_ + kk * 32 + lq * 8;
#pragma unroll
    for (int n = 0; n < 8; ++n) {
      short8 bv = *(const short8*)(vb + n * 16 * S_);
      oa[n] = MFMA(pa, bv, oa[n]);
    }
  }
#pragma unroll
  for (int n = 0; n < 8; ++n)
#pragma unroll
    for (int r = 0; r < 4; ++r) {
      int row = qrow0 + lq * 4 + r;
      int col = h * HD_ + n * 16 + l15;
      size_t idx = ((size_t)(b * S_ + row)) * DA_ + col;
      out[idx] = bf2f(h1[idx]) + oa[n][r];
    }
}

// ---------------------------------------------------------------- host
extern "C" void kernel_launch(void* const* d_in, const int* in_sizes, int n_in,
                              void* d_out, int out_size, void* d_ws, size_t ws_size,
                              hipStream_t stream) {
  const float* x    = (const float*)d_in[0];
  const float* mask = (const float*)d_in[1];
  const int*   lens = (const int*)d_in[2];
  const float* Wih0 = (const float*)d_in[3];
  const float* Whh0 = (const float*)d_in[4];
  const float* b0   = (const float*)d_in[5];
  const float* Wih1 = (const float*)d_in[6];
  const float* Whh1 = (const float*)d_in[7];
  const float* b1   = (const float*)d_in[8];
  const float* Wq   = (const float*)d_in[9];
  const float* bq   = (const float*)d_in[10];
  const float* Wk   = (const float*)d_in[11];
  const float* bk   = (const float*)d_in[12];
  const float* Wv   = (const float*)d_in[13];
  const float* bv   = (const float*)d_in[14];

  const size_t SZ_wb_ih1 = (size_t)2 * G4_ * DA_ * 2;
  const size_t SZ_wb_hh  = (size_t)2 * G4_ * H_ * 2;
  const size_t SZ_wb_qkv = (size_t)DA_ * DA_ * 2;
  const size_t SZ_tok_bf = (size_t)B_ * S_ * DA_ * 2;
  const size_t SZ_h_ex   = (size_t)2 * 2 * 32 * SLAB8_;  // 114,688
  const size_t SZ_xbf    = (size_t)B_ * S_ * DM_ * 2;
  const size_t SZ_wb_ih0 = (size_t)2 * G4_ * DM_ * 2;
  const size_t SZ_regA   = SZ_xbf + SZ_wb_ih0 + SZ_wb_hh;
  const size_t SZ_xp_f32 = (size_t)2 * B_ * S_ * G4_ * 4;
  const size_t SZ_xp_bf  = SZ_xp_f32 / 2;

  const size_t persist = SZ_wb_ih1 + SZ_wb_hh + 3 * SZ_wb_qkv + 2 * SZ_tok_bf
                       + SZ_h_ex;
  const size_t need_A = persist + SZ_regA + SZ_xp_f32;
  const bool xpf32 = (ws_size >= need_A + 4096);

  char* ws = (char*)d_ws;
  size_t off = 0;
  auto alloc = [&](size_t bytes) { char* p = ws + off; off += bytes; return p; };

  unsigned short* wb_ih1 = (unsigned short*)alloc(SZ_wb_ih1);
  unsigned short* wb_hh1 = (unsigned short*)alloc(SZ_wb_hh);
  unsigned short* wb_q   = (unsigned short*)alloc(SZ_wb_qkv);
  unsigned short* wb_k   = (unsigned short*)alloc(SZ_wb_qkv);
  unsigned short* wb_v   = (unsigned short*)alloc(SZ_wb_qkv);
  unsigned short* h0bf   = (unsigned short*)alloc(SZ_tok_bf);
  unsigned short* h1bf   = (unsigned short*)alloc(SZ_tok_bf);
  char*           h_ex   = alloc(SZ_h_ex);

  char* regA = alloc(SZ_regA);
  unsigned short* xbf    = (unsigned short*)regA;
  unsigned short* wb_ih0 = (unsigned short*)(regA + SZ_xbf);
  unsigned short* wb_hh0 = (unsigned short*)(regA + SZ_xbf + SZ_wb_ih0);
  unsigned short* qbf    = (unsigned short*)regA;

  char* regB = alloc(xpf32 ? SZ_xp_f32 : SZ_xp_bf);
  void*           xp     = (void*)regB;
  unsigned short* kbf    = (unsigned short*)regB;
  unsigned short* vtbf   = (unsigned short*)(regB + SZ_tok_bf);

  // zero exchange slabs (tag 0 == valid h_0 = 0 for layer 0)
  hipMemsetAsync(h_ex, 0, SZ_h_ex, stream);

  auto cast = [&](const float* s, unsigned short* d, size_t n) {
    int n4 = (int)(n / 4);
    cast_f32_bf16<<<(n4 + 255) / 256, 256, 0, stream>>>(s, d, n4);
  };
  cast(Wih0, wb_ih0, (size_t)2 * G4_ * DM_);
  cast(Whh0, wb_hh0, (size_t)2 * G4_ * H_);
  cast(Wih1, wb_ih1, (size_t)2 * G4_ * DA_);
  cast(Whh1, wb_hh1, (size_t)2 * G4_ * H_);
  cast(Wq, wb_q, (size_t)DA_ * DA_);
  cast(Wk, wb_k, (size_t)DA_ * DA_);
  cast(Wv, wb_v, (size_t)DA_ * DA_);
  cast(x, xbf, (size_t)B_ * S_ * DM_);

  const int M = B_ * S_;  // 8192
  const size_t xp_dir_elems = (size_t)32 * S_ * 1280;  // = M * G4_ per dir

  // layer-0 input projection -> xp scatter layout
  if (xpf32) {
    gemm_abt<3><<<(M / 128) * (G4_ / 128), 256, 0, stream>>>(
        xbf, wb_ih0, b0, xp, M, G4_, DM_);
    gemm_abt<3><<<(M / 128) * (G4_ / 128), 256, 0, stream>>>(
        xbf, wb_ih0 + (size_t)G4_ * DM_, b0 + G4_,
        (float*)xp + xp_dir_elems, M, G4_, DM_);
    bilstm_layer<true><<<64, 320, 0, stream>>>(xp, wb_hh0, lens, h_ex, h0bf);
  } else {
    gemm_abt<4><<<(M / 128) * (G4_ / 128), 256, 0, stream>>>(
        xbf, wb_ih0, b0, xp, M, G4_, DM_);
    gemm_abt<4><<<(M / 128) * (G4_ / 128), 256, 0, stream>>>(
        xbf, wb_ih0 + (size_t)G4_ * DM_, b0 + G4_,
        (unsigned short*)xp + xp_dir_elems, M, G4_, DM_);
    bilstm_layer<false><<<64, 320, 0, stream>>>(xp, wb_hh0, lens, h_ex, h0bf);
  }

  // reset exchange slabs (tags restart for layer 1)
  hipMemsetAsync(h_ex, 0, SZ_h_ex, stream);

  // layer-1 input projection (reuse xp) + recurrence
  if (xpf32) {
    gemm_abt<3><<<(M / 128) * (G4_ / 128), 256, 0, stream>>>(
        h0bf, wb_ih1, b1, xp, M, G4_, DA_);
    gemm_abt<3><<<(M / 128) * (G4_ / 128), 256, 0, stream>>>(
        h0bf, wb_ih1 + (size_t)G4_ * DA_, b1 + G4_,
        (float*)xp + xp_dir_elems, M, G4_, DA_);
    bilstm_layer<true><<<64, 320, 0, stream>>>(xp, wb_hh1, lens, h_ex, h1bf);
  } else {
    gemm_abt<4><<<(M / 128) * (G4_ / 128), 256, 0, stream>>>(
        h0bf, wb_ih1, b1, xp, M, G4_, DA_);
    gemm_abt<4><<<(M / 128) * (G4_ / 128), 256, 0, stream>>>(
        h0bf, wb_ih1 + (size_t)G4_ * DA_, b1 + G4_,
        (unsigned short*)xp + xp_dir_elems, M, G4_, DA_);
    bilstm_layer<false><<<64, 320, 0, stream>>>(xp, wb_hh1, lens, h_ex, h1bf);
  }

  // QKV (qbf overlays dead xbf/wb_ih0; kbf/vtbf overlay dead xp)
  gemm_abt<1><<<(M / 128) * (DA_ / 128), 256, 0, stream>>>(
      h1bf, wb_q, bq, qbf, M, DA_, DA_);
  gemm_abt<1><<<(M / 128) * (DA_ / 128), 256, 0, stream>>>(
      h1bf, wb_k, bk, kbf, M, DA_, DA_);
  gemm_abt<2><<<(M / 128) * (DA_ / 128), 256, 0, stream>>>(
      h1bf, wb_v, bv, vtbf, M, DA_, DA_);
  attn_fused<<<B_ * NH_ * 8, 256, 0, stream>>>(qbf, kbf, vtbf, mask, h1bf,
                                               (float*)d_out);
}

// Round 10
// 4213.254 us; speedup vs baseline: 1.9172x; 1.9172x over previous
//
#include <hip/hip_runtime.h>

typedef __attribute__((ext_vector_type(8))) short short8;
typedef __attribute__((ext_vector_type(4))) float f32x4;
typedef __attribute__((ext_vector_type(4))) unsigned int u32x4;

#define MFMA(a,b,c) __builtin_amdgcn_mfma_f32_16x16x32_bf16((a),(b),(c),0,0,0)

#define B_  16
#define S_  512
#define DM_ 768
#define H_  640
#define G4_ 2560
#define DA_ 1280
#define NH_ 10
#define HD_ 128
#define U_   20      // hidden units per WG

static __device__ __forceinline__ unsigned short f2bf(float v) {
  unsigned u = __builtin_bit_cast(unsigned, v);
  u = (u + 0x7fffu + ((u >> 16) & 1u)) >> 16;
  return (unsigned short)u;
}
static __device__ __forceinline__ float bf2f(unsigned short u) {
  return __builtin_bit_cast(float, (unsigned)u << 16);
}
static __device__ __forceinline__ float sigm(float x) { return 1.0f / (1.0f + __expf(-x)); }
static __device__ __forceinline__ float tanh_c(float x) {
  x = fminf(fmaxf(x, -15.0f), 15.0f);
  float e = __expf(2.0f * x);
  return (e - 1.0f) / (e + 1.0f);
}

// ---- LLC-coherent (L1/L2-bypassing) access helpers --------------------------
static __device__ __forceinline__ u32x4 load_coh16(const void* p) {
  u32x4 r;
  asm volatile("global_load_dwordx4 %0, %1, off sc0 sc1"
               : "=v"(r) : "v"(p) : "memory");
  return r;
}
static __device__ __forceinline__ void store_coh64(void* p, unsigned long long v) {
  asm volatile("global_store_dwordx2 %0, %1, off sc0 sc1"
               :: "v"(p), "v"(v) : "memory");
}
static __device__ __forceinline__ void store_coh_u32(void* p, unsigned v) {
  asm volatile("global_store_dword %0, %1, off sc0 sc1"
               :: "v"(p), "v"(v) : "memory");
}
// fused load+wait: returned register is architecturally valid
static __device__ __forceinline__ unsigned poll_u32(const void* p) {
  unsigned r;
  asm volatile("global_load_dword %0, %1, off sc0 sc1\n\ts_waitcnt vmcnt(0)"
               : "=v"(r) : "v"(p) : "memory");
  return r;
}
#define WAIT_VM0() asm volatile("s_waitcnt vmcnt(0)" ::: "memory")

// barrier that does NOT drain vmcnt (keeps out-stores/prefetches in flight)
static __device__ __forceinline__ void bar_lgkm() {
  __builtin_amdgcn_sched_barrier(0);
  asm volatile("s_waitcnt lgkmcnt(0)\n\ts_barrier" ::: "memory");
  __builtin_amdgcn_sched_barrier(0);
}

// ---------------------------------------------------------------- cast f32->bf16
__global__ __launch_bounds__(256)
void cast_f32_bf16(const float* __restrict__ src, unsigned short* __restrict__ dst, int n4) {
  int i = blockIdx.x * 256 + threadIdx.x;
  if (i >= n4) return;
  float4 v = reinterpret_cast<const float4*>(src)[i];
  ushort4 o;
  o.x = f2bf(v.x); o.y = f2bf(v.y); o.z = f2bf(v.z); o.w = f2bf(v.w);
  reinterpret_cast<ushort4*>(dst)[i] = o;
}

// ---------------------------------------------------------------- GEMM  C = A @ W^T + bias
// OUT_MODE 1: bf16 C[M][N]; 2: bf16 per-head-transposed V; 3: f32 xp-scatter
// [slice][t][b][gate*20+u]; 4: bf16 same layout.
__device__ __forceinline__ void gload_lds16(void* lds, const void* g) {
  __builtin_amdgcn_global_load_lds(
      (const __attribute__((address_space(1))) unsigned int*)g,
      (__attribute__((address_space(3))) unsigned int*)lds, 16, 0, 0);
}

template<int OUT_MODE>
__global__ __launch_bounds__(256)
void gemm_abt(const unsigned short* __restrict__ A, const unsigned short* __restrict__ W,
              const float* __restrict__ bias, void* __restrict__ Cout,
              int M, int N, int K) {
  __shared__ unsigned short lA[128 * 32];
  __shared__ unsigned short lB[128 * 32];
  const int tid = threadIdx.x;
  const int lane = tid & 63, wid = tid >> 6;
  const int nbn = N >> 7;
  const int mi = blockIdx.x / nbn, ni = blockIdx.x % nbn;
  const int l15 = lane & 15, lq = lane >> 4;

  f32x4 acc[4][4] = {};

  for (int k0 = 0; k0 < K; k0 += 32) {
#pragma unroll
    for (int part = 0; part < 2; ++part) {
      int linear = part * 256 + tid;
      int r = linear >> 2, cc = linear & 3;
      const unsigned short* ga = A + (size_t)(mi * 128 + r) * K + k0 + cc * 8;
      const unsigned short* gb = W + (size_t)(ni * 128 + r) * K + k0 + cc * 8;
      gload_lds16(&lA[(part * 256 + wid * 64) * 8], ga);
      gload_lds16(&lB[(part * 256 + wid * 64) * 8], gb);
    }
    __syncthreads();
    const int wm = (wid >> 1) * 64, wn = (wid & 1) * 64;
    short8 af[4], bfr[4];
#pragma unroll
    for (int m = 0; m < 4; ++m)
      af[m] = *(const short8*)&lA[(wm + m * 16 + l15) * 32 + lq * 8];
#pragma unroll
    for (int n = 0; n < 4; ++n)
      bfr[n] = *(const short8*)&lB[(wn + n * 16 + l15) * 32 + lq * 8];
#pragma unroll
    for (int m = 0; m < 4; ++m)
#pragma unroll
      for (int n = 0; n < 4; ++n)
        acc[m][n] = MFMA(af[m], bfr[n], acc[m][n]);
    __syncthreads();
  }

  const int wm = (wid >> 1) * 64, wn = (wid & 1) * 64;
#pragma unroll
  for (int n = 0; n < 4; ++n) {
    int col = ni * 128 + wn + n * 16 + l15;
    float bv = bias[col];
#pragma unroll
    for (int m = 0; m < 4; ++m) {
#pragma unroll
      for (int r = 0; r < 4; ++r) {
        int row = mi * 128 + wm + m * 16 + lq * 4 + r;
        float v = acc[m][n][r] + bv;
        if (OUT_MODE == 1) {
          ((unsigned short*)Cout)[(size_t)row * N + col] = f2bf(v);
        } else if (OUT_MODE == 2) {
          int bb = row >> 9, s = row & 511, hh = col >> 7, d = col & 127;
          ((unsigned short*)Cout)[(((size_t)(bb * NH_ + hh) * HD_ + d) << 9) + s] = f2bf(v);
        } else {
          int gate = col / 640, unit = col % 640;
          int slice = unit / 20, uu = unit % 20;
          int bb = row >> 9, tt = row & 511;
          size_t idx = (((size_t)slice * S_ + tt) * B_ + bb) * 80 + gate * 20 + uu;
          if (OUT_MODE == 3) ((float*)Cout)[idx] = v;
          else               ((unsigned short*)Cout)[idx] = f2bf(v);
        }
      }
    }
  }
}

// ---------------------------------------------------------------- persistent BiLSTM layer
// EXACT R3 protocol (best measured: 1715us/layer) with three drain removals:
//  1. xp prefetch issued at step BOTTOM (was inside phase-1 vmcnt(0) wait)
//  2. publish: gates->staged LDS; wave4 fires 80x8B coherent stores + drains ITS
//     OWN wave only + sets flag (was 320 scalar stores + all-thread drain)
//  3. bottom barrier is lgkm-only: out-stores/prefetch stay in flight
// Image: h_ex[dir][parity][16 b][640 u] bf16 (20480 B). Consumer: 4x16B/thread
// bulk read after wave0's 32-flag poll (1 dword/lane/retry). Flags monotonic
// across layers via fb; h_ex memset between layers (h_0 = 0).
template<bool XPF32>
__global__ __launch_bounds__(320)
void bilstm_layer(const void* __restrict__ xp_,            // [2][32][S][16][80]
                  const unsigned short* __restrict__ whh_g,// [2][2560][640] bf16
                  const int* __restrict__ lengths,
                  char* __restrict__ h_ex,                 // [2][2][20480 B]
                  int* __restrict__ flags, int fb,         // [64][32] ints
                  unsigned short* __restrict__ out_bf)     // [B*S][1280] bf16
{
  __shared__ unsigned short whh[80 * 648];
  __shared__ unsigned short hbuf[16 * 648];
  __shared__ float pre[16 * 80];
  __shared__ float xpbuf[16 * 80];   // bf16 plan reuses low half
  __shared__ unsigned short staged[16 * 20];
  __shared__ int len_s[16];

  const int tid = threadIdx.x;
  const int lane = tid & 63, wv = tid >> 6;
  const int wg = blockIdx.x;
  const int dir = wg >> 5, slice = wg & 31;
  const int J0 = slice * U_;
  const int l15 = lane & 15, lq = lane >> 4;

  // stage Whh slab (rows = gate*20 + unit), R3 layout
  for (int c = tid; c < 80 * 160; c += 320) {
    int r = c / 160, c4 = c % 160;
    int grow = (r / 20) * H_ + J0 + (r % 20);
    *(ushort4*)&whh[r * 648 + c4 * 4] =
        *(const ushort4*)&whh_g[((size_t)dir * G4_ + grow) * H_ + c4 * 4];
  }
  if (tid < 16) len_s[tid] = lengths[tid];
  __syncthreads();

  const int gb = tid / 20, gu = tid % 20;
  float c_st = 0.f, h_st = 0.f;

  const char* xps = (const char*)xp_ +
      ((size_t)dir * 32 + slice) * S_ * 1280 * (XPF32 ? 4 : 2);

  float4  xv_f; ushort4 xv_h;
  {
    int t0 = dir ? (S_ - 1) : 0;
    if (XPF32) xv_f = *(const float4*)(xps + ((size_t)t0 * 1280 + tid * 4) * 4);
    else       xv_h = *(const ushort4*)(xps + ((size_t)t0 * 1280 + tid * 4) * 2);
  }

  for (int s = 0; s < S_; ++s) {
    const int t = dir ? (S_ - 1 - s) : s;

    // ---- phase 1: coherent bulk read of h image (parity s&1) -> hbuf
    {
      const char* src = h_ex + (size_t)((dir * 2 + (s & 1)) * 20480);
      u32x4 hv[4]; int bs[4], os[4];
#pragma unroll
      for (int j = 0; j < 4; ++j) {
        int c = tid + j * 320;          // 1280 chunks of 16B
        bs[j] = c / 80; os[j] = c % 80;
        hv[j] = load_coh16(src + (size_t)bs[j] * 1280 + os[j] * 16);
      }
      WAIT_VM0();
      __builtin_amdgcn_sched_barrier(0);
#pragma unroll
      for (int j = 0; j < 4; ++j)
        *(u32x4*)&hbuf[bs[j] * 648 + os[j] * 8] = hv[j];
    }
    if (XPF32) *(float4*)&xpbuf[tid * 4] = xv_f;
    else       *(ushort4*)&((unsigned short*)xpbuf)[tid * 4] = xv_h;
    __syncthreads();   // A: hbuf + xpbuf ready

    // ---- MFMA: pre[b][gate*20+u], two independent chains (R3)
    f32x4 acc0 = {0.f, 0.f, 0.f, 0.f}, acc1 = {0.f, 0.f, 0.f, 0.f};
#pragma unroll
    for (int kk = 0; kk < 20; kk += 2) {
      short8 a0 = *(const short8*)&hbuf[l15 * 648 + kk * 32 + lq * 8];
      short8 b0v = *(const short8*)&whh[(wv * 16 + l15) * 648 + kk * 32 + lq * 8];
      acc0 = MFMA(a0, b0v, acc0);
      short8 a1 = *(const short8*)&hbuf[l15 * 648 + (kk + 1) * 32 + lq * 8];
      short8 b1v = *(const short8*)&whh[(wv * 16 + l15) * 648 + (kk + 1) * 32 + lq * 8];
      acc1 = MFMA(a1, b1v, acc1);
    }
#pragma unroll
    for (int r = 0; r < 4; ++r)
      pre[(lq * 4 + r) * 80 + wv * 16 + l15] = acc0[r] + acc1[r];
    __syncthreads();   // B: pre ready

    // ---- gates (thread owns (gb,gu)); h -> staged LDS only
    float yv;
    {
      float xi, xf, xg, xo;
      if (XPF32) {
        xi = xpbuf[gb * 80 + gu];
        xf = xpbuf[gb * 80 + 20 + gu];
        xg = xpbuf[gb * 80 + 40 + gu];
        xo = xpbuf[gb * 80 + 60 + gu];
      } else {
        const unsigned short* xb = (const unsigned short*)xpbuf;
        xi = bf2f(xb[gb * 80 + gu]);
        xf = bf2f(xb[gb * 80 + 20 + gu]);
        xg = bf2f(xb[gb * 80 + 40 + gu]);
        xo = bf2f(xb[gb * 80 + 60 + gu]);
      }
      float gi = pre[gb * 80 + gu]      + xi;
      float gf = pre[gb * 80 + 20 + gu] + xf;
      float gg = pre[gb * 80 + 40 + gu] + xg;
      float go = pre[gb * 80 + 60 + gu] + xo;
      float i_ = sigm(gi), f_ = sigm(gf);
      float g_ = tanh_c(gg), o_ = sigm(go);
      float c2 = f_ * c_st + i_ * g_;
      float h2 = o_ * tanh_c(c2);
      bool valid = t < len_s[gb];
      c_st = valid ? c2 : c_st;
      h_st = valid ? h2 : h_st;
      staged[gb * 20 + gu] = f2bf(h_st);
      yv = valid ? h_st : 0.f;
    }
    __syncthreads();   // C: staged complete

    if (s + 1 < S_) {
      if (wv == 4) {
        // ---- publish: 80x8B coherent stores + OWN-wave drain + flag
        char* img = h_ex + (size_t)((dir * 2 + ((s + 1) & 1)) * 20480);
        {
          int b = lane / 5, q = lane % 5;
          unsigned long long d = *(const unsigned long long*)&staged[b * 20 + q * 4];
          store_coh64(img + (size_t)b * 1280 + slice * 40 + q * 8, d);
        }
        if (lane < 16) {
          int k2 = 64 + lane, b = k2 / 5, q = k2 % 5;
          unsigned long long d = *(const unsigned long long*)&staged[b * 20 + q * 4];
          store_coh64(img + (size_t)b * 1280 + slice * 40 + q * 8, d);
        }
        WAIT_VM0();   // wave4's stores only
        if (lane == 0)
          store_coh_u32(flags + (size_t)(dir * 32 + slice) * 32,
                        (unsigned)(fb + s + 1));
      } else if (wv == 0) {
        // ---- poll: 32 flags, 1 dword/lane/retry (fused load+wait)
        const int tgt = fb + s + 1;
        const int* fp = flags + (size_t)(dir * 32 + (lane & 31)) * 32;
        for (;;) {
          unsigned v = poll_u32(fp);
          if (__all((int)v >= tgt)) break;
        }
      }
    }

    // ---- off-critical-path: output store + next xp prefetch (never drained here)
    out_bf[((size_t)(gb * S_ + t)) * DA_ + dir * H_ + J0 + gu] = f2bf(yv);
    {
      int tn = dir ? (S_ - 2 - s) : (s + 1);
      tn = tn < 0 ? 0 : (tn > S_ - 1 ? S_ - 1 : tn);
      if (XPF32) xv_f = *(const float4*)(xps + ((size_t)tn * 1280 + tid * 4) * 4);
      else       xv_h = *(const ushort4*)(xps + ((size_t)tn * 1280 + tid * 4) * 2);
    }
    bar_lgkm();        // D: go-signal shared; vmem stays in flight
  }
}

// ---------------------------------------------------------------- fused attention + residual
__global__ __launch_bounds__(256)
void attn_fused(const unsigned short* __restrict__ q, const unsigned short* __restrict__ k,
                const unsigned short* __restrict__ vT, const float* __restrict__ mask,
                const unsigned short* __restrict__ h1, float* __restrict__ out)
{
  __shared__ unsigned short p_lds[64 * 512];
  const int tid = threadIdx.x, lane = tid & 63, wid = tid >> 6;
  const int bx = blockIdx.x;
  const int b = bx / 80, rem = bx % 80, h = rem / 8, qt = rem % 8;
  const int l15 = lane & 15, lq = lane >> 4;
  const int qrow0 = qt * 64 + wid * 16;

  short8 qf[4];
  {
    const unsigned short* qb = q + ((size_t)(b * S_ + qrow0 + l15)) * DA_ + h * HD_ + lq * 8;
#pragma unroll
    for (int ks = 0; ks < 4; ++ks) qf[ks] = *(const short8*)(qb + ks * 32);
  }
  f32x4 sc[32];
#pragma unroll
  for (int nt = 0; nt < 32; ++nt) {
    f32x4 a = {0.f, 0.f, 0.f, 0.f};
    const unsigned short* kb = k + ((size_t)(b * S_ + nt * 16 + l15)) * DA_ + h * HD_ + lq * 8;
#pragma unroll
    for (int ks = 0; ks < 4; ++ks) {
      short8 bf = *(const short8*)(kb + ks * 32);
      a = MFMA(qf[ks], bf, a);
    }
    sc[nt] = a;
  }
  const float scl = 0.08838834764831845f;  // 1/sqrt(128)
  float mx[4] = {-1e30f, -1e30f, -1e30f, -1e30f};
#pragma unroll
  for (int nt = 0; nt < 32; ++nt) {
    float mv = mask[b * S_ + nt * 16 + l15];
#pragma unroll
    for (int r = 0; r < 4; ++r) {
      float v = sc[nt][r] * scl + mv;
      sc[nt][r] = v;
      mx[r] = fmaxf(mx[r], v);
    }
  }
#pragma unroll
  for (int r = 0; r < 4; ++r) {
    mx[r] = fmaxf(mx[r], __shfl_xor(mx[r], 1));
    mx[r] = fmaxf(mx[r], __shfl_xor(mx[r], 2));
    mx[r] = fmaxf(mx[r], __shfl_xor(mx[r], 4));
    mx[r] = fmaxf(mx[r], __shfl_xor(mx[r], 8));
  }
  float sm[4] = {0.f, 0.f, 0.f, 0.f};
#pragma unroll
  for (int nt = 0; nt < 32; ++nt)
#pragma unroll
    for (int r = 0; r < 4; ++r) {
      float p = __expf(sc[nt][r] - mx[r]);
      sc[nt][r] = p; sm[r] += p;
    }
#pragma unroll
  for (int r = 0; r < 4; ++r) {
    sm[r] += __shfl_xor(sm[r], 1);
    sm[r] += __shfl_xor(sm[r], 2);
    sm[r] += __shfl_xor(sm[r], 4);
    sm[r] += __shfl_xor(sm[r], 8);
    sm[r] = 1.0f / sm[r];
  }
#pragma unroll
  for (int nt = 0; nt < 32; ++nt)
#pragma unroll
    for (int r = 0; r < 4; ++r) {
      int row = wid * 16 + lq * 4 + r;
      int byte = row * 1024 + (nt * 16 + l15) * 2;
      byte ^= (row & 7) << 4;
      *(unsigned short*)((char*)p_lds + byte) = f2bf(sc[nt][r] * sm[r]);
    }
  __syncthreads();

  f32x4 oa[8] = {};
#pragma unroll
  for (int kk = 0; kk < 16; ++kk) {
    int row = wid * 16 + l15;
    int byte = row * 1024 + (kk * 32 + lq * 8) * 2;
    byte ^= (row & 7) << 4;
    short8 pa = *(const short8*)((char*)p_lds + byte);
    const unsigned short* vb = vT + ((size_t)(b * NH_ + h) * HD_ + l15) * S_ + kk * 32 + lq * 8;
#pragma unroll
    for (int n = 0; n < 8; ++n) {
      short8 bv = *(const short8*)(vb + n * 16 * S_);
      oa[n] = MFMA(pa, bv, oa[n]);
    }
  }
#pragma unroll
  for (int n = 0; n < 8; ++n)
#pragma unroll
    for (int r = 0; r < 4; ++r) {
      int row = qrow0 + lq * 4 + r;
      int col = h * HD_ + n * 16 + l15;
      size_t idx = ((size_t)(b * S_ + row)) * DA_ + col;
      out[idx] = bf2f(h1[idx]) + oa[n][r];
    }
}

// ---------------------------------------------------------------- host
extern "C" void kernel_launch(void* const* d_in, const int* in_sizes, int n_in,
                              void* d_out, int out_size, void* d_ws, size_t ws_size,
                              hipStream_t stream) {
  const float* x    = (const float*)d_in[0];
  const float* mask = (const float*)d_in[1];
  const int*   lens = (const int*)d_in[2];
  const float* Wih0 = (const float*)d_in[3];
  const float* Whh0 = (const float*)d_in[4];
  const float* b0   = (const float*)d_in[5];
  const float* Wih1 = (const float*)d_in[6];
  const float* Whh1 = (const float*)d_in[7];
  const float* b1   = (const float*)d_in[8];
  const float* Wq   = (const float*)d_in[9];
  const float* bq   = (const float*)d_in[10];
  const float* Wk   = (const float*)d_in[11];
  const float* bk   = (const float*)d_in[12];
  const float* Wv   = (const float*)d_in[13];
  const float* bv   = (const float*)d_in[14];

  const size_t SZ_wb_ih1 = (size_t)2 * G4_ * DA_ * 2;
  const size_t SZ_wb_hh  = (size_t)2 * G4_ * H_ * 2;
  const size_t SZ_wb_qkv = (size_t)DA_ * DA_ * 2;
  const size_t SZ_tok_bf = (size_t)B_ * S_ * DA_ * 2;
  const size_t SZ_h_ex   = (size_t)2 * 2 * 20480;       // 81,920
  const size_t SZ_flags  = (size_t)64 * 32 * 4;         //  8,192
  const size_t SZ_xbf    = (size_t)B_ * S_ * DM_ * 2;
  const size_t SZ_wb_ih0 = (size_t)2 * G4_ * DM_ * 2;
  const size_t SZ_regA   = SZ_xbf + SZ_wb_ih0 + SZ_wb_hh;
  const size_t SZ_xp_f32 = (size_t)2 * B_ * S_ * G4_ * 4;
  const size_t SZ_xp_bf  = SZ_xp_f32 / 2;

  const size_t persist = SZ_wb_ih1 + SZ_wb_hh + 3 * SZ_wb_qkv + 2 * SZ_tok_bf
                       + SZ_h_ex + SZ_flags;
  const size_t need_A = persist + SZ_regA + SZ_xp_f32;
  const bool xpf32 = (ws_size >= need_A + 4096);

  char* ws = (char*)d_ws;
  size_t off = 0;
  auto alloc = [&](size_t bytes) { char* p = ws + off; off += bytes; return p; };

  unsigned short* wb_ih1 = (unsigned short*)alloc(SZ_wb_ih1);
  unsigned short* wb_hh1 = (unsigned short*)alloc(SZ_wb_hh);
  unsigned short* wb_q   = (unsigned short*)alloc(SZ_wb_qkv);
  unsigned short* wb_k   = (unsigned short*)alloc(SZ_wb_qkv);
  unsigned short* wb_v   = (unsigned short*)alloc(SZ_wb_qkv);
  unsigned short* h0bf   = (unsigned short*)alloc(SZ_tok_bf);
  unsigned short* h1bf   = (unsigned short*)alloc(SZ_tok_bf);
  char*           h_ex   = alloc(SZ_h_ex);
  int*            flags  = (int*)alloc(SZ_flags);

  char* regA = alloc(SZ_regA);
  unsigned short* xbf    = (unsigned short*)regA;
  unsigned short* wb_ih0 = (unsigned short*)(regA + SZ_xbf);
  unsigned short* wb_hh0 = (unsigned short*)(regA + SZ_xbf + SZ_wb_ih0);
  unsigned short* qbf    = (unsigned short*)regA;

  char* regB = alloc(xpf32 ? SZ_xp_f32 : SZ_xp_bf);
  void*           xp     = (void*)regB;
  unsigned short* kbf    = (unsigned short*)regB;
  unsigned short* vtbf   = (unsigned short*)(regB + SZ_tok_bf);

  // zero h_ex + flags (adjacent); flags count monotonically across layers
  hipMemsetAsync(h_ex, 0, SZ_h_ex + SZ_flags, stream);

  auto cast = [&](const float* s, unsigned short* d, size_t n) {
    int n4 = (int)(n / 4);
    cast_f32_bf16<<<(n4 + 255) / 256, 256, 0, stream>>>(s, d, n4);
  };
  cast(Wih0, wb_ih0, (size_t)2 * G4_ * DM_);
  cast(Whh0, wb_hh0, (size_t)2 * G4_ * H_);
  cast(Wih1, wb_ih1, (size_t)2 * G4_ * DA_);
  cast(Whh1, wb_hh1, (size_t)2 * G4_ * H_);
  cast(Wq, wb_q, (size_t)DA_ * DA_);
  cast(Wk, wb_k, (size_t)DA_ * DA_);
  cast(Wv, wb_v, (size_t)DA_ * DA_);
  cast(x, xbf, (size_t)B_ * S_ * DM_);

  const int M = B_ * S_;  // 8192
  const size_t xp_dir_elems = (size_t)32 * S_ * 1280;  // = M * G4_ per dir

  // layer-0 input projection -> xp scatter layout
  if (xpf32) {
    gemm_abt<3><<<(M / 128) * (G4_ / 128), 256, 0, stream>>>(
        xbf, wb_ih0, b0, xp, M, G4_, DM_);
    gemm_abt<3><<<(M / 128) * (G4_ / 128), 256, 0, stream>>>(
        xbf, wb_ih0 + (size_t)G4_ * DM_, b0 + G4_,
        (float*)xp + xp_dir_elems, M, G4_, DM_);
    bilstm_layer<true><<<64, 320, 0, stream>>>(xp, wb_hh0, lens, h_ex, flags, 0, h0bf);
  } else {
    gemm_abt<4><<<(M / 128) * (G4_ / 128), 256, 0, stream>>>(
        xbf, wb_ih0, b0, xp, M, G4_, DM_);
    gemm_abt<4><<<(M / 128) * (G4_ / 128), 256, 0, stream>>>(
        xbf, wb_ih0 + (size_t)G4_ * DM_, b0 + G4_,
        (unsigned short*)xp + xp_dir_elems, M, G4_, DM_);
    bilstm_layer<false><<<64, 320, 0, stream>>>(xp, wb_hh0, lens, h_ex, flags, 0, h0bf);
  }

  // reset h image for layer 1 (flags monotonic, not reset)
  hipMemsetAsync(h_ex, 0, SZ_h_ex, stream);

  // layer-1 input projection (reuse xp) + recurrence
  if (xpf32) {
    gemm_abt<3><<<(M / 128) * (G4_ / 128), 256, 0, stream>>>(
        h0bf, wb_ih1, b1, xp, M, G4_, DA_);
    gemm_abt<3><<<(M / 128) * (G4_ / 128), 256, 0, stream>>>(
        h0bf, wb_ih1 + (size_t)G4_ * DA_, b1 + G4_,
        (float*)xp + xp_dir_elems, M, G4_, DA_);
    bilstm_layer<true><<<64, 320, 0, stream>>>(xp, wb_hh1, lens, h_ex, flags, S_, h1bf);
  } else {
    gemm_abt<4><<<(M / 128) * (G4_ / 128), 256, 0, stream>>>(
        h0bf, wb_ih1, b1, xp, M, G4_, DA_);
    gemm_abt<4><<<(M / 128) * (G4_ / 128), 256, 0, stream>>>(
        h0bf, wb_ih1 + (size_t)G4_ * DA_, b1 + G4_,
        (unsigned short*)xp + xp_dir_elems, M, G4_, DA_);
    bilstm_layer<false><<<64, 320, 0, stream>>>(xp, wb_hh1, lens, h_ex, flags, S_, h1bf);
  }

  // QKV (qbf overlays dead xbf/wb_ih0; kbf/vtbf overlay dead xp)
  gemm_abt<1><<<(M / 128) * (DA_ / 128), 256, 0, stream>>>(
      h1bf, wb_q, bq, qbf, M, DA_, DA_);
  gemm_abt<1><<<(M / 128) * (DA_ / 128), 256, 0, stream>>>(
      h1bf, wb_k, bk, kbf, M, DA_, DA_);
  gemm_abt<2><<<(M / 128) * (DA_ / 128), 256, 0, stream>>>(
      h1bf, wb_v, bv, vtbf, M, DA_, DA_);
  attn_fused<<<B_ * NH_ * 8, 256, 0, stream>>>(qbf, kbf, vtbf, mask, h1bf,
                                               (float*)d_out);
}